// Round 1
// baseline (39.623 us; speedup 1.0000x reference)
//
#include <hip/hip_runtime.h>
#include <math.h>

#define N 2048
#define BATCH 32
#define BLOCK 256
#define SLICES 32                  // blocks per batch row
#define I_PER_BLOCK (N / SLICES)   // 64 output elements per block

// Each block: one (batch, i-slice). Stage x_b in LDS, compute row min/max,
// then 4 threads cooperate per output i, each covering 512 j's via float4.
__global__ __launch_bounds__(BLOCK) void rank1_attn_kernel(
    const float* __restrict__ x, float* __restrict__ y) {
    __shared__ float sx[N];
    __shared__ float sred[8];      // [0..3] wave maxes, [4..7] wave mins

    const int b     = blockIdx.x / SLICES;
    const int slice = blockIdx.x % SLICES;
    const int tid   = threadIdx.x;

    const float* xb = x + b * N;

    // ---- stage row into LDS, track partial min/max ----
    float pmax = -1e30f, pmin = 1e30f;
    const float4* xb4 = reinterpret_cast<const float4*>(xb);
    float4* sx4 = reinterpret_cast<float4*>(sx);
#pragma unroll
    for (int k = 0; k < 2; ++k) {
        float4 v = xb4[tid + k * BLOCK];
        sx4[tid + k * BLOCK] = v;
        pmax = fmaxf(pmax, fmaxf(fmaxf(v.x, v.y), fmaxf(v.z, v.w)));
        pmin = fminf(pmin, fminf(fminf(v.x, v.y), fminf(v.z, v.w)));
    }
    // wave (64-lane) butterfly reduce
#pragma unroll
    for (int off = 32; off >= 1; off >>= 1) {
        pmax = fmaxf(pmax, __shfl_xor(pmax, off));
        pmin = fminf(pmin, __shfl_xor(pmin, off));
    }
    const int wave = tid >> 6;
    if ((tid & 63) == 0) { sred[wave] = pmax; sred[4 + wave] = pmin; }
    __syncthreads();
    const float xmax = fmaxf(fmaxf(sred[0], sred[1]), fmaxf(sred[2], sred[3]));
    const float xmin = fminf(fminf(sred[4], sred[5]), fminf(sred[6], sred[7]));

    // ---- per-thread setup: 4 threads (sub=0..3) per output i ----
    const int iLocal = tid >> 2;       // 0..63
    const int sub    = tid & 3;        // 0..3
    const int i      = slice * I_PER_BLOCK + iLocal;

    const float LOG2E = 1.4426950408889634f;
    const float xi = sx[i];
    const float tl = xi * (LOG2E / 16.0f);              // t * log2(e)
    const float m2 = tl * (xi >= 0.0f ? xmax : xmin);   // max_j (t*x_j) in log2 units

    float num0 = 0.f, num1 = 0.f, num2 = 0.f, num3 = 0.f;
    float den0 = 0.f, den1 = 0.f, den2 = 0.f, den3 = 0.f;

    const float4* s4 = reinterpret_cast<const float4*>(sx);
    // j = jj*16 + sub*4 + {0,1,2,3}; jj in [0,128) -> 512 j's per thread
#pragma unroll 4
    for (int jj = 0; jj < N / 16; ++jj) {
        float4 v = s4[jj * 4 + sub];
        float e0 = exp2f(fmaf(tl, v.x, -m2));
        float e1 = exp2f(fmaf(tl, v.y, -m2));
        float e2 = exp2f(fmaf(tl, v.z, -m2));
        float e3 = exp2f(fmaf(tl, v.w, -m2));
        den0 += e0; den1 += e1; den2 += e2; den3 += e3;
        num0 = fmaf(e0, v.x, num0);
        num1 = fmaf(e1, v.y, num1);
        num2 = fmaf(e2, v.z, num2);
        num3 = fmaf(e3, v.w, num3);
    }
    float num = (num0 + num1) + (num2 + num3);
    float den = (den0 + den1) + (den2 + den3);

    // reduce across the 4 cooperating lanes (consecutive lanes in one wave)
    num += __shfl_xor(num, 1); den += __shfl_xor(den, 1);
    num += __shfl_xor(num, 2); den += __shfl_xor(den, 2);

    if (sub == 0) y[b * N + i] = num / den;
}

extern "C" void kernel_launch(void* const* d_in, const int* in_sizes, int n_in,
                              void* d_out, int out_size, void* d_ws, size_t ws_size,
                              hipStream_t stream) {
    const float* x = (const float*)d_in[0];
    float* y = (float*)d_out;
    dim3 grid(BATCH * SLICES);
    dim3 block(BLOCK);
    rank1_attn_kernel<<<grid, block, 0, stream>>>(x, y);
}

// Round 2
// 24.424 us; speedup vs baseline: 1.6223x; 1.6223x over previous
//
#include <hip/hip_runtime.h>
#include <math.h>

#define N 2048
#define BATCH 32
#define BLOCK 256
#define SLICES 64                  // blocks per batch row
#define I_PER_BLOCK (N / SLICES)   // 32 output elements per block
#define SUBS 8                     // threads cooperating per output i

// Each block: one (batch, i-slice). Stage x_b in LDS, compute row min/max,
// then 8 threads cooperate per output i, each covering 256 j's via float4.
__global__ __launch_bounds__(BLOCK, 8) void rank1_attn_kernel(
    const float* __restrict__ x, float* __restrict__ y) {
    __shared__ float sx[N];
    __shared__ float sred[8];      // [0..3] wave maxes, [4..7] wave mins

    const int b     = blockIdx.x / SLICES;
    const int slice = blockIdx.x % SLICES;
    const int tid   = threadIdx.x;

    const float* xb = x + b * N;

    // ---- stage row into LDS, track partial min/max ----
    float pmax = -1e30f, pmin = 1e30f;
    const float4* xb4 = reinterpret_cast<const float4*>(xb);
    float4* sx4 = reinterpret_cast<float4*>(sx);
#pragma unroll
    for (int k = 0; k < 2; ++k) {
        float4 v = xb4[tid + k * BLOCK];
        sx4[tid + k * BLOCK] = v;
        pmax = fmaxf(pmax, fmaxf(fmaxf(v.x, v.y), fmaxf(v.z, v.w)));
        pmin = fminf(pmin, fminf(fminf(v.x, v.y), fminf(v.z, v.w)));
    }
    // wave (64-lane) butterfly reduce
#pragma unroll
    for (int off = 32; off >= 1; off >>= 1) {
        pmax = fmaxf(pmax, __shfl_xor(pmax, off));
        pmin = fminf(pmin, __shfl_xor(pmin, off));
    }
    const int wave = tid >> 6;
    if ((tid & 63) == 0) { sred[wave] = pmax; sred[4 + wave] = pmin; }
    __syncthreads();
    const float xmax = fmaxf(fmaxf(sred[0], sred[1]), fmaxf(sred[2], sred[3]));
    const float xmin = fminf(fminf(sred[4], sred[5]), fminf(sred[6], sred[7]));

    // ---- per-thread setup: SUBS threads per output i ----
    const int iLocal = tid / SUBS;      // 0..31
    const int sub    = tid % SUBS;      // 0..7
    const int i      = slice * I_PER_BLOCK + iLocal;

    const float LOG2E = 1.4426950408889634f;
    const float xi = sx[i];
    const float tl = xi * (LOG2E / 16.0f);              // t * log2(e)
    const float m2 = tl * (xi >= 0.0f ? xmax : xmin);   // max_j (t*x_j) in log2 units

    float num0 = 0.f, num1 = 0.f, num2 = 0.f, num3 = 0.f;
    float den0 = 0.f, den1 = 0.f, den2 = 0.f, den3 = 0.f;

    const float4* s4 = reinterpret_cast<const float4*>(sx);
    // j = jj*(SUBS*4) + sub*4 + {0,1,2,3}; jj in [0, N/(SUBS*4)) -> 256 j's/thread
#pragma unroll 8
    for (int jj = 0; jj < N / (SUBS * 4); ++jj) {
        float4 v = s4[jj * SUBS + sub];
        float e0 = __builtin_amdgcn_exp2f(fmaf(tl, v.x, -m2));
        float e1 = __builtin_amdgcn_exp2f(fmaf(tl, v.y, -m2));
        float e2 = __builtin_amdgcn_exp2f(fmaf(tl, v.z, -m2));
        float e3 = __builtin_amdgcn_exp2f(fmaf(tl, v.w, -m2));
        den0 += e0; den1 += e1; den2 += e2; den3 += e3;
        num0 = fmaf(e0, v.x, num0);
        num1 = fmaf(e1, v.y, num1);
        num2 = fmaf(e2, v.z, num2);
        num3 = fmaf(e3, v.w, num3);
    }
    float num = (num0 + num1) + (num2 + num3);
    float den = (den0 + den1) + (den2 + den3);

    // reduce across the 8 cooperating lanes (consecutive lanes in one wave)
    num += __shfl_xor(num, 1); den += __shfl_xor(den, 1);
    num += __shfl_xor(num, 2); den += __shfl_xor(den, 2);
    num += __shfl_xor(num, 4); den += __shfl_xor(den, 4);

    if (sub == 0) y[b * N + i] = num / den;
}

extern "C" void kernel_launch(void* const* d_in, const int* in_sizes, int n_in,
                              void* d_out, int out_size, void* d_ws, size_t ws_size,
                              hipStream_t stream) {
    const float* x = (const float*)d_in[0];
    float* y = (float*)d_out;
    dim3 grid(BATCH * SLICES);
    dim3 block(BLOCK);
    rank1_attn_kernel<<<grid, block, 0, stream>>>(x, y);
}